// Round 1
// baseline (400.494 us; speedup 1.0000x reference)
//
#include <hip/hip_runtime.h>
#include <hip/hip_bf16.h>

#define LL 4096
#define NH 16
#define DM 1024
#define DK 64
#define MTOT 8192
#define PI_F 3.14159265358979323846f

typedef short short8 __attribute__((ext_vector_type(8)));
typedef float f32x4 __attribute__((ext_vector_type(4)));

__device__ __forceinline__ unsigned short f2bf(float x){
  union { float f; unsigned int u; } v; v.f = x;
  unsigned int r = v.u + 0x7FFFu + ((v.u >> 16) & 1u);
  return (unsigned short)(r >> 16);
}
__device__ __forceinline__ float bf2f(unsigned short u){
  union { unsigned int u; float f; } v; v.u = ((unsigned int)u) << 16; return v.f;
}

// ---------------- converts ----------------
__global__ void k_conv_x(const float* __restrict__ in, unsigned short* __restrict__ out, int n4){
  int i = blockIdx.x*256 + threadIdx.x;
  if (i >= n4) return;
  float4 v = ((const float4*)in)[i];
  ushort4 o; o.x=f2bf(v.x); o.y=f2bf(v.y); o.z=f2bf(v.z); o.w=f2bf(v.w);
  ((ushort4*)out)[i] = o;
}

__global__ void k_conv_x_split(const float* __restrict__ in, unsigned short* __restrict__ hi,
                               unsigned short* __restrict__ lo, int n4){
  int i = blockIdx.x*256 + threadIdx.x;
  if (i >= n4) return;
  float4 v = ((const float4*)in)[i];
  ushort4 oh, ol;
  oh.x=f2bf(v.x); ol.x=f2bf(v.x - bf2f(oh.x));
  oh.y=f2bf(v.y); ol.y=f2bf(v.y - bf2f(oh.y));
  oh.z=f2bf(v.z); ol.z=f2bf(v.z - bf2f(oh.z));
  oh.w=f2bf(v.w); ol.w=f2bf(v.w - bf2f(oh.w));
  ((ushort4*)hi)[i] = oh;
  ((ushort4*)lo)[i] = ol;
}

// transpose-convert W [k][n] f32 -> Wt [n][k] bf16 (hi for all 4, lo for z<2)
__global__ void k_conv_wt(const float* __restrict__ W0, const float* __restrict__ W1,
                          const float* __restrict__ W2, const float* __restrict__ W3,
                          unsigned short* __restrict__ hi_base, unsigned short* __restrict__ lo_base){
  const float* W = (blockIdx.z==0)?W0:(blockIdx.z==1)?W1:(blockIdx.z==2)?W2:W3;
  unsigned short* oh = hi_base + (size_t)blockIdx.z*DM*DM;
  unsigned short* ol = (blockIdx.z<2) ? (lo_base + (size_t)blockIdx.z*DM*DM) : nullptr;
  __shared__ unsigned short th[64][65];
  __shared__ unsigned short tl[64][65];
  int n0 = blockIdx.x*64, k0 = blockIdx.y*64;
  for (int i=0;i<16;i++){
    int g = i*256 + threadIdx.x;
    int kr = g>>6, nc = g&63;
    float x = W[(size_t)(k0+kr)*DM + n0+nc];
    unsigned short h = f2bf(x);
    th[kr][nc] = h;
    tl[kr][nc] = f2bf(x - bf2f(h));
  }
  __syncthreads();
  for (int i=0;i<16;i++){
    int g = i*256 + threadIdx.x;
    int nr = g>>6, kc = g&63;
    oh[(size_t)(n0+nr)*DM + k0+kc] = th[kc][nr];
    if (ol) ol[(size_t)(n0+nr)*DM + k0+kc] = tl[kc][nr];
  }
}

// ---------------- plain bf16 GEMM (V projection, output projection) ----------------
// MODE 1: write bf16, head-major [b*NH+h][l][d]; MODE 2: write f32 flat [m][n]
template<int MODE>
__global__ __launch_bounds__(256) void k_gemm_plain(
    const short* __restrict__ A, const short* __restrict__ Bt,
    const float* __restrict__ bias, float* __restrict__ Cf, unsigned short* __restrict__ Cb)
{
  __shared__ short As[128][72];
  __shared__ short Bs[128][72];
  const int m0 = blockIdx.x*128, n0 = blockIdx.y*128;
  const int tid = threadIdx.x;
  const int wave = tid>>6, lane = tid&63;
  const int wm = (wave>>1)*64, wn = (wave&1)*64;
  const int li = lane&15, lk4 = lane>>4;
  f32x4 acc[4][4] = {};
  for (int kt=0; kt<16; ++kt){
    #pragma unroll
    for (int i=0;i<4;i++){
      int g = i*256+tid;
      int r = g>>3, c = (g&7)*8;
      *(short8*)&As[r][c] = *(const short8*)&A[(size_t)(m0+r)*DM + kt*64 + c];
      *(short8*)&Bs[r][c] = *(const short8*)&Bt[(size_t)(n0+r)*DM + kt*64 + c];
    }
    __syncthreads();
    #pragma unroll
    for (int kk=0; kk<64; kk+=32){
      short8 af[4], bfv[4];
      #pragma unroll
      for (int mi=0;mi<4;mi++) af[mi] = *(const short8*)&As[wm+mi*16+li][kk+lk4*8];
      #pragma unroll
      for (int ni=0;ni<4;ni++) bfv[ni] = *(const short8*)&Bs[wn+ni*16+li][kk+lk4*8];
      #pragma unroll
      for (int mi=0;mi<4;mi++)
        #pragma unroll
        for (int ni=0;ni<4;ni++)
          acc[mi][ni] = __builtin_amdgcn_mfma_f32_16x16x32_bf16(af[mi], bfv[ni], acc[mi][ni], 0,0,0);
    }
    __syncthreads();
  }
  #pragma unroll
  for (int mi=0;mi<4;mi++){
    #pragma unroll
    for (int ni=0;ni<4;ni++){
      const int col = n0 + wn + ni*16 + li;
      const float bv = bias[col];
      const int mbase = m0 + wm + mi*16 + lk4*4;
      #pragma unroll
      for (int r=0;r<4;r++){
        const int row = mbase + r;
        float v = acc[mi][ni][r] + bv;
        if (MODE==2){
          Cf[(size_t)row*DM + col] = v;
        } else {
          int b = row>>12, l = row&(LL-1), h = col>>6, d = col&63;
          Cb[(((size_t)(b*NH+h))*LL + l)*DK + d] = f2bf(v);
        }
      }
    }
  }
}

// ---------------- split-precision GEMM (Q, K projections) ----------------
// C = (Ahi+Alo)@(Bhi+Blo)^T approx via 3 MFMA passes. Output f32, layout [b*NH+h][d][l].
__global__ __launch_bounds__(256) void k_gemm_split(
    const short* __restrict__ Ahi, const short* __restrict__ Alo,
    const short* __restrict__ Bhi, const short* __restrict__ Blo,
    const float* __restrict__ bias, float* __restrict__ Ct)
{
  __shared__ short AsH[128][40];
  __shared__ short AsL[128][40];
  __shared__ short BsH[128][40];
  __shared__ short BsL[128][40];
  const int m0 = blockIdx.x*128, n0 = blockIdx.y*128;
  const int tid = threadIdx.x;
  const int wave = tid>>6, lane = tid&63;
  const int wm = (wave>>1)*64, wn = (wave&1)*64;
  const int li = lane&15, lk4 = lane>>4;
  f32x4 acc[4][4] = {};
  for (int kt=0; kt<32; ++kt){
    #pragma unroll
    for (int i=0;i<2;i++){
      int g = i*256+tid;
      int r = g>>2, c = (g&3)*8;
      size_t ga = (size_t)(m0+r)*DM + kt*32 + c;
      size_t gb = (size_t)(n0+r)*DM + kt*32 + c;
      *(short8*)&AsH[r][c] = *(const short8*)&Ahi[ga];
      *(short8*)&AsL[r][c] = *(const short8*)&Alo[ga];
      *(short8*)&BsH[r][c] = *(const short8*)&Bhi[gb];
      *(short8*)&BsL[r][c] = *(const short8*)&Blo[gb];
    }
    __syncthreads();
    short8 ah[4], al[4], bh[4], bl[4];
    #pragma unroll
    for (int mi=0;mi<4;mi++){
      ah[mi]=*(const short8*)&AsH[wm+mi*16+li][lk4*8];
      al[mi]=*(const short8*)&AsL[wm+mi*16+li][lk4*8];
    }
    #pragma unroll
    for (int ni=0;ni<4;ni++){
      bh[ni]=*(const short8*)&BsH[wn+ni*16+li][lk4*8];
      bl[ni]=*(const short8*)&BsL[wn+ni*16+li][lk4*8];
    }
    #pragma unroll
    for (int mi=0;mi<4;mi++)
      #pragma unroll
      for (int ni=0;ni<4;ni++){
        f32x4 a = acc[mi][ni];
        a = __builtin_amdgcn_mfma_f32_16x16x32_bf16(ah[mi], bh[ni], a, 0,0,0);
        a = __builtin_amdgcn_mfma_f32_16x16x32_bf16(ah[mi], bl[ni], a, 0,0,0);
        a = __builtin_amdgcn_mfma_f32_16x16x32_bf16(al[mi], bh[ni], a, 0,0,0);
        acc[mi][ni] = a;
      }
    __syncthreads();
  }
  // epilogue: Ct [b*NH+h][d][l] f32, contiguous float4 over l
  #pragma unroll
  for (int mi=0;mi<4;mi++){
    #pragma unroll
    for (int ni=0;ni<4;ni++){
      const int col = n0 + wn + ni*16 + li;
      const float bv = bias[col];
      const int mbase = m0 + wm + mi*16 + lk4*4;
      const int b = mbase>>12, l0 = mbase&(LL-1);
      const int h = col>>6, d = col&63;
      float4 o;
      o.x = acc[mi][ni][0]+bv; o.y = acc[mi][ni][1]+bv;
      o.z = acc[mi][ni][2]+bv; o.w = acc[mi][ni][3]+bv;
      *(float4*)&Ct[(((size_t)(b*NH+h))*DK + d)*LL + l0] = o;
    }
  }
}

// ---------------- FFT ----------------
// Stockham radix-2, 4096-pt, 256 threads, ping-pong in LDS (buf = float2[8192] = 64KB)
__device__ __forceinline__ void fft12(float2* buf, int tid, float sign){
  int cur = 0;
  for (int s=0;s<12;s++){
    int Ls = 1<<s;
    const float2* a = buf + cur*4096;
    float2* b = buf + (cur^1)*4096;
    #pragma unroll
    for (int i=0;i<8;i++){
      int k = i*256+tid;
      int j = k & (Ls-1);
      float sn, cs;
      __sincosf(sign*PI_F*(float)j/(float)Ls, &sn, &cs);
      float2 u = a[k], v = a[k+2048];
      float tr = cs*v.x - sn*v.y;
      float ti = cs*v.y + sn*v.x;
      int dst = ((k>>s)<<(s+1)) | j;
      b[dst]    = make_float2(u.x+tr, u.y+ti);
      b[dst+Ls] = make_float2(u.x-tr, u.y-ti);
    }
    __syncthreads();
    cur ^= 1;
  }
  // result in buf[0..4095]
}

// forward: one block per (b,h,d). X = Q + iK, FFT, hermitian split, accumulate S += qhat*conj(khat)
__global__ __launch_bounds__(256) void k_fft_fwd(const float* __restrict__ Qt, const float* __restrict__ Kt,
                                                 float* __restrict__ S){
  __shared__ float2 buf[8192];
  const int bh = blockIdx.x >> 6;
  const int d  = blockIdx.x & 63;
  const int tid = threadIdx.x;
  const size_t base = ((size_t)bh*DK + d)*LL;
  for (int i=0;i<16;i++){
    int l = i*256+tid;
    buf[l] = make_float2(Qt[base + l], Kt[base + l]);
  }
  __syncthreads();
  fft12(buf, tid, -1.0f);
  float* Sp = S + (size_t)bh*LL*2;
  for (int i=0;i<16;i++){
    int f = i*256+tid;
    float2 A2 = buf[f];
    float2 B2 = buf[(LL-f)&(LL-1)];
    float qr = 0.5f*(A2.x + B2.x), qi = 0.5f*(A2.y - B2.y);
    float kr = 0.5f*(A2.y + B2.y), ki = -0.5f*(A2.x - B2.x);
    float pr = qr*kr + qi*ki;   // q * conj(k)
    float pi = qi*kr - qr*ki;
    atomicAdd(&Sp[f*2],   pr);
    atomicAdd(&Sp[f*2+1], pi);
  }
}

// inverse + top-8 + softmax: one block per (b,h)
__global__ __launch_bounds__(256) void k_ifft_topk(const float* __restrict__ S,
                                                   float* __restrict__ w8, int* __restrict__ idx8){
  __shared__ float2 buf[8192];
  const int bh = blockIdx.x;
  const int tid = threadIdx.x;
  const float2* Sp = (const float2*)(S + (size_t)bh*LL*2);
  for (int i=0;i<16;i++){ int f=i*256+tid; buf[f] = Sp[f]; }
  __syncthreads();
  fft12(buf, tid, +1.0f);
  // carve scratch from second half of buf (free after fft)
  float* c    = (float*)(buf + 4096);
  float* rv   = c + 4096;
  int*   ri   = (int*)(c + 4352);
  float* topv = c + 4608;
  int*   topi = (int*)(c + 4616);
  const float scale = 1.0f/((float)LL * (float)DK);
  for (int i=0;i<16;i++){ int t=i*256+tid; c[t] = buf[t].x * scale; }
  __syncthreads();
  for (int kk=0; kk<8; kk++){
    float bv = -3.4e38f; int bi = 0;
    for (int i=0;i<16;i++){
      int t = i*256+tid;
      float v = c[t];
      if (v > bv || (v == bv && t < bi)) { bv = v; bi = t; }
    }
    rv[tid]=bv; ri[tid]=bi;
    __syncthreads();
    for (int off=128; off>0; off>>=1){
      if (tid < off){
        float ov = rv[tid+off]; int oi = ri[tid+off];
        if (ov > rv[tid] || (ov == rv[tid] && oi < ri[tid])) { rv[tid]=ov; ri[tid]=oi; }
      }
      __syncthreads();
    }
    if (tid==0){ topv[kk]=rv[0]; topi[kk]=ri[0]; c[ri[0]] = -3.0e38f; }
    __syncthreads();
  }
  if (tid==0){
    float m = topv[0];
    float e[8], sum=0.f;
    for (int k=0;k<8;k++){ e[k]=__expf(topv[k]-m); sum+=e[k]; }
    for (int k=0;k<8;k++){ w8[bh*8+k]=e[k]/sum; idx8[bh*8+k]=topi[k]; }
  }
}

// ---------------- roll-gather: Ob[b,l,h,d] = sum_k w_k * V[b,h,(l+idx_k)%L,d], bf16 out ----------------
__global__ __launch_bounds__(256) void k_gather(const unsigned short* __restrict__ Vh,
                                                const float* __restrict__ w8, const int* __restrict__ idx8,
                                                unsigned short* __restrict__ Ob){
  const int blk = blockIdx.x;      // 2048 = 32 bh * 64 l-chunks
  const int bh = blk >> 6;
  const int l0 = (blk & 63) * 64;
  const int b = bh >> 4, h = bh & 15;
  float w[8]; int ix[8];
  #pragma unroll
  for (int k=0;k<8;k++){ w[k]=w8[bh*8+k]; ix[k]=idx8[bh*8+k]; }
  const int tid = threadIdx.x;
  for (int it=0; it<16; ++it){
    int e = it*256 + tid;
    int lo = e >> 6, d = e & 63;
    int l = l0 + lo;
    float acc = 0.f;
    #pragma unroll
    for (int k=0;k<8;k++){
      int sl = (l + ix[k]) & (LL-1);
      acc += w[k] * bf2f(Vh[((size_t)bh*LL + sl)*DK + d]);
    }
    Ob[((size_t)(b*LL + l))*DM + h*DK + d] = f2bf(acc);
  }
}

// ---------------- launch ----------------
extern "C" void kernel_launch(void* const* d_in, const int* in_sizes, int n_in,
                              void* d_out, int out_size, void* d_ws, size_t ws_size,
                              hipStream_t stream) {
  const float* query = (const float*)d_in[0];
  const float* key   = (const float*)d_in[1];
  const float* value = (const float*)d_in[2];
  const float* Wq = (const float*)d_in[3];
  const float* bq = (const float*)d_in[4];
  const float* Wk = (const float*)d_in[5];
  const float* bk = (const float*)d_in[6];
  const float* Wv = (const float*)d_in[7];
  const float* bv = (const float*)d_in[8];
  const float* Wo = (const float*)d_in[9];
  const float* bo = (const float*)d_in[10];
  float* out = (float*)d_out;

  char* ws = (char*)d_ws;
  size_t off = 0;
  auto take = [&](size_t b)->char*{ char* p = ws + off; off += (b + 255) & ~(size_t)255; return p; };
  short* Xhi = (short*)take((size_t)MTOT*DM*2);        // 16MB (also reused as Ob)
  short* Xlo = (short*)take((size_t)MTOT*DM*2);        // 16MB
  short* Wth = (short*)take((size_t)4*DM*DM*2);        // 8MB  (Wq,Wk,Wv,Wo transposed hi)
  short* Wtl = (short*)take((size_t)2*DM*DM*2);        // 4MB  (Wq,Wk transposed lo)
  float* Qt  = (float*)take((size_t)2*NH*DK*LL*4);     // 32MB [bh][d][l]
  float* Kt  = (float*)take((size_t)2*NH*DK*LL*4);     // 32MB
  unsigned short* Vh = (unsigned short*)take((size_t)2*NH*LL*DK*2); // 16MB [bh][l][d]
  float* S   = (float*)take((size_t)32*LL*2*4);        // 1MB
  float* w8  = (float*)take(32*8*4);
  int*  idx8 = (int*)take(32*8*4);

  const int n4 = MTOT*DM/4;

  hipMemsetAsync(S, 0, (size_t)32*LL*2*4, stream);
  k_conv_wt<<<dim3(16,16,4),256,0,stream>>>(Wq,Wk,Wv,Wo,(unsigned short*)Wth,(unsigned short*)Wtl);

  k_conv_x_split<<<n4/256,256,0,stream>>>(query,(unsigned short*)Xhi,(unsigned short*)Xlo,n4);
  k_gemm_split<<<dim3(64,8),256,0,stream>>>(Xhi, Xlo, Wth, Wtl, bq, Qt);

  k_conv_x_split<<<n4/256,256,0,stream>>>(key,(unsigned short*)Xhi,(unsigned short*)Xlo,n4);
  k_gemm_split<<<dim3(64,8),256,0,stream>>>(Xhi, Xlo, Wth + (size_t)DM*DM, Wtl + (size_t)DM*DM, bk, Kt);

  k_conv_x<<<n4/256,256,0,stream>>>(value,(unsigned short*)Xhi,n4);
  k_gemm_plain<1><<<dim3(64,8),256,0,stream>>>(Xhi, Wth + (size_t)2*DM*DM, bv, nullptr, Vh);

  k_fft_fwd<<<2048,256,0,stream>>>(Qt, Kt, S);
  k_ifft_topk<<<32,256,0,stream>>>(S, w8, idx8);
  k_gather<<<2048,256,0,stream>>>(Vh, w8, idx8, (unsigned short*)Xhi);

  k_gemm_plain<2><<<dim3(64,8),256,0,stream>>>(Xhi, Wth + (size_t)3*DM*DM, bo, out, nullptr);
}

// Round 2
// 275.829 us; speedup vs baseline: 1.4520x; 1.4520x over previous
//
#include <hip/hip_runtime.h>
#include <hip/hip_bf16.h>

#define LL 4096
#define NH 16
#define DM 1024
#define DK 64
#define MTOT 8192
#define PI_F 3.14159265358979323846f

typedef short short8 __attribute__((ext_vector_type(8)));
typedef float f32x4 __attribute__((ext_vector_type(4)));

__device__ __forceinline__ unsigned short f2bf(float x){
  union { float f; unsigned int u; } v; v.f = x;
  unsigned int r = v.u + 0x7FFFu + ((v.u >> 16) & 1u);
  return (unsigned short)(r >> 16);
}
__device__ __forceinline__ float bf2f(unsigned short u){
  union { unsigned int u; float f; } v; v.u = ((unsigned int)u) << 16; return v.f;
}

// ---------------- converts ----------------
__global__ void k_conv_x(const float* __restrict__ in, unsigned short* __restrict__ out, int n4){
  int i = blockIdx.x*256 + threadIdx.x;
  if (i >= n4) return;
  float4 v = ((const float4*)in)[i];
  ushort4 o; o.x=f2bf(v.x); o.y=f2bf(v.y); o.z=f2bf(v.z); o.w=f2bf(v.w);
  ((ushort4*)out)[i] = o;
}

__global__ void k_conv_x_split(const float* __restrict__ in, unsigned short* __restrict__ hi,
                               unsigned short* __restrict__ lo, int n4){
  int i = blockIdx.x*256 + threadIdx.x;
  if (i >= n4) return;
  float4 v = ((const float4*)in)[i];
  ushort4 oh, ol;
  oh.x=f2bf(v.x); ol.x=f2bf(v.x - bf2f(oh.x));
  oh.y=f2bf(v.y); ol.y=f2bf(v.y - bf2f(oh.y));
  oh.z=f2bf(v.z); ol.z=f2bf(v.z - bf2f(oh.z));
  oh.w=f2bf(v.w); ol.w=f2bf(v.w - bf2f(oh.w));
  ((ushort4*)hi)[i] = oh;
  ((ushort4*)lo)[i] = ol;
}

// transpose-convert W [k][n] f32 -> Wt [n][k] bf16 (hi for all 4, lo for z<2)
__global__ void k_conv_wt(const float* __restrict__ W0, const float* __restrict__ W1,
                          const float* __restrict__ W2, const float* __restrict__ W3,
                          unsigned short* __restrict__ hi_base, unsigned short* __restrict__ lo_base){
  const float* W = (blockIdx.z==0)?W0:(blockIdx.z==1)?W1:(blockIdx.z==2)?W2:W3;
  unsigned short* oh = hi_base + (size_t)blockIdx.z*DM*DM;
  unsigned short* ol = (blockIdx.z<2) ? (lo_base + (size_t)blockIdx.z*DM*DM) : nullptr;
  __shared__ unsigned short th[64][65];
  __shared__ unsigned short tl[64][65];
  int n0 = blockIdx.x*64, k0 = blockIdx.y*64;
  for (int i=0;i<16;i++){
    int g = i*256 + threadIdx.x;
    int kr = g>>6, nc = g&63;
    float x = W[(size_t)(k0+kr)*DM + n0+nc];
    unsigned short h = f2bf(x);
    th[kr][nc] = h;
    tl[kr][nc] = f2bf(x - bf2f(h));
  }
  __syncthreads();
  for (int i=0;i<16;i++){
    int g = i*256 + threadIdx.x;
    int nr = g>>6, kc = g&63;
    oh[(size_t)(n0+nr)*DM + k0+kc] = th[kc][nr];
    if (ol) ol[(size_t)(n0+nr)*DM + k0+kc] = tl[kc][nr];
  }
}

// ---------------- plain bf16 GEMM (V projection, output projection) ----------------
template<int MODE>
__global__ __launch_bounds__(256) void k_gemm_plain(
    const short* __restrict__ A, const short* __restrict__ Bt,
    const float* __restrict__ bias, float* __restrict__ Cf, unsigned short* __restrict__ Cb)
{
  __shared__ short As[128][72];
  __shared__ short Bs[128][72];
  const int m0 = blockIdx.x*128, n0 = blockIdx.y*128;
  const int tid = threadIdx.x;
  const int wave = tid>>6, lane = tid&63;
  const int wm = (wave>>1)*64, wn = (wave&1)*64;
  const int li = lane&15, lk4 = lane>>4;
  f32x4 acc[4][4] = {};
  for (int kt=0; kt<16; ++kt){
    #pragma unroll
    for (int i=0;i<4;i++){
      int g = i*256+tid;
      int r = g>>3, c = (g&7)*8;
      *(short8*)&As[r][c] = *(const short8*)&A[(size_t)(m0+r)*DM + kt*64 + c];
      *(short8*)&Bs[r][c] = *(const short8*)&Bt[(size_t)(n0+r)*DM + kt*64 + c];
    }
    __syncthreads();
    #pragma unroll
    for (int kk=0; kk<64; kk+=32){
      short8 af[4], bfv[4];
      #pragma unroll
      for (int mi=0;mi<4;mi++) af[mi] = *(const short8*)&As[wm+mi*16+li][kk+lk4*8];
      #pragma unroll
      for (int ni=0;ni<4;ni++) bfv[ni] = *(const short8*)&Bs[wn+ni*16+li][kk+lk4*8];
      #pragma unroll
      for (int mi=0;mi<4;mi++)
        #pragma unroll
        for (int ni=0;ni<4;ni++)
          acc[mi][ni] = __builtin_amdgcn_mfma_f32_16x16x32_bf16(af[mi], bfv[ni], acc[mi][ni], 0,0,0);
    }
    __syncthreads();
  }
  #pragma unroll
  for (int mi=0;mi<4;mi++){
    #pragma unroll
    for (int ni=0;ni<4;ni++){
      const int col = n0 + wn + ni*16 + li;
      const float bv = bias[col];
      const int mbase = m0 + wm + mi*16 + lk4*4;
      #pragma unroll
      for (int r=0;r<4;r++){
        const int row = mbase + r;
        float v = acc[mi][ni][r] + bv;
        if (MODE==2){
          Cf[(size_t)row*DM + col] = v;
        } else {
          int b = row>>12, l = row&(LL-1), h = col>>6, d = col&63;
          Cb[(((size_t)(b*NH+h))*LL + l)*DK + d] = f2bf(v);
        }
      }
    }
  }
}

// ---------------- split-precision GEMM (Q, K projections) ----------------
__global__ __launch_bounds__(256) void k_gemm_split(
    const short* __restrict__ Ahi, const short* __restrict__ Alo,
    const short* __restrict__ Bhi, const short* __restrict__ Blo,
    const float* __restrict__ bias, float* __restrict__ Ct)
{
  __shared__ short AsH[128][40];
  __shared__ short AsL[128][40];
  __shared__ short BsH[128][40];
  __shared__ short BsL[128][40];
  const int m0 = blockIdx.x*128, n0 = blockIdx.y*128;
  const int tid = threadIdx.x;
  const int wave = tid>>6, lane = tid&63;
  const int wm = (wave>>1)*64, wn = (wave&1)*64;
  const int li = lane&15, lk4 = lane>>4;
  f32x4 acc[4][4] = {};
  for (int kt=0; kt<32; ++kt){
    #pragma unroll
    for (int i=0;i<2;i++){
      int g = i*256+tid;
      int r = g>>2, c = (g&3)*8;
      size_t ga = (size_t)(m0+r)*DM + kt*32 + c;
      size_t gb = (size_t)(n0+r)*DM + kt*32 + c;
      *(short8*)&AsH[r][c] = *(const short8*)&Ahi[ga];
      *(short8*)&AsL[r][c] = *(const short8*)&Alo[ga];
      *(short8*)&BsH[r][c] = *(const short8*)&Bhi[gb];
      *(short8*)&BsL[r][c] = *(const short8*)&Blo[gb];
    }
    __syncthreads();
    short8 ah[4], al[4], bh[4], bl[4];
    #pragma unroll
    for (int mi=0;mi<4;mi++){
      ah[mi]=*(const short8*)&AsH[wm+mi*16+li][lk4*8];
      al[mi]=*(const short8*)&AsL[wm+mi*16+li][lk4*8];
    }
    #pragma unroll
    for (int ni=0;ni<4;ni++){
      bh[ni]=*(const short8*)&BsH[wn+ni*16+li][lk4*8];
      bl[ni]=*(const short8*)&BsL[wn+ni*16+li][lk4*8];
    }
    #pragma unroll
    for (int mi=0;mi<4;mi++)
      #pragma unroll
      for (int ni=0;ni<4;ni++){
        f32x4 a = acc[mi][ni];
        a = __builtin_amdgcn_mfma_f32_16x16x32_bf16(ah[mi], bh[ni], a, 0,0,0);
        a = __builtin_amdgcn_mfma_f32_16x16x32_bf16(ah[mi], bl[ni], a, 0,0,0);
        a = __builtin_amdgcn_mfma_f32_16x16x32_bf16(al[mi], bh[ni], a, 0,0,0);
        acc[mi][ni] = a;
      }
    __syncthreads();
  }
  #pragma unroll
  for (int mi=0;mi<4;mi++){
    #pragma unroll
    for (int ni=0;ni<4;ni++){
      const int col = n0 + wn + ni*16 + li;
      const float bv = bias[col];
      const int mbase = m0 + wm + mi*16 + lk4*4;
      const int b = mbase>>12, l0 = mbase&(LL-1);
      const int h = col>>6, d = col&63;
      float4 o;
      o.x = acc[mi][ni][0]+bv; o.y = acc[mi][ni][1]+bv;
      o.z = acc[mi][ni][2]+bv; o.w = acc[mi][ni][3]+bv;
      *(float4*)&Ct[(((size_t)(b*NH+h))*DK + d)*LL + l0] = o;
    }
  }
}

// ---------------- radix-16 register FFT (4096-pt, 256 threads, 16 elems/thread) ----------------
__device__ __forceinline__ float2 cmul(float2 a, float2 b){
  return make_float2(a.x*b.x - a.y*b.y, a.x*b.y + a.y*b.x);
}
__device__ __forceinline__ int swz(int i){ return i ^ ((i>>4)&15); }

// v * (cos(pi*k/8) + sgn*i*sin(pi*k/8)); k is a compile-time literal after unroll
__device__ __forceinline__ float2 ctw(float2 v, int k, float sgn){
  float c, s;
  switch(k){
    case 0: return v;
    case 1: c= 0.92387953251f; s= 0.38268343236f; break;
    case 2: c= 0.70710678119f; s= 0.70710678119f; break;
    case 3: c= 0.38268343236f; s= 0.92387953251f; break;
    case 4: c= 0.f;            s= 1.f;            break;
    case 6: c=-0.70710678119f; s= 0.70710678119f; break;
    default:c=-0.92387953251f; s=-0.38268343236f; break; // k==9
  }
  s *= sgn;
  return make_float2(v.x*c - v.y*s, v.x*s + v.y*c);
}

template<int SGN>
__device__ __forceinline__ void dft16(float2 x[16]){
  const float sg = (float)SGN;
  // level 1: radix-4 over m2 (stride 4); z[m1][q] stored at x[m1+4q]
  #pragma unroll
  for (int m1=0;m1<4;m1++){
    float2 a=x[m1], b=x[m1+4], c=x[m1+8], d=x[m1+12];
    float acx=a.x+c.x, acy=a.y+c.y, sx=a.x-c.x, sy=a.y-c.y;
    float bdx=b.x+d.x, bdy=b.y+d.y, tx=b.x-d.x, ty=b.y-d.y;
    float ix=-sg*ty, iy=sg*tx;            // SGN*i*(b-d)
    x[m1]    = make_float2(acx+bdx, acy+bdy);
    x[m1+4]  = make_float2(sx+ix,  sy+iy);
    x[m1+8]  = make_float2(acx-bdx, acy-bdy);
    x[m1+12] = make_float2(sx-ix,  sy-iy);
  }
  // level 2: twiddle by w16^{m1*p1}, then radix-4 over m1; y[p1+4p2]
  float2 y[16];
  #pragma unroll
  for (int p1=0;p1<4;p1++){
    float2 a = x[4*p1+0];
    float2 b = ctw(x[4*p1+1], p1,   sg);
    float2 c = ctw(x[4*p1+2], 2*p1, sg);
    float2 d = ctw(x[4*p1+3], 3*p1, sg);
    float acx=a.x+c.x, acy=a.y+c.y, sx=a.x-c.x, sy=a.y-c.y;
    float bdx=b.x+d.x, bdy=b.y+d.y, tx=b.x-d.x, ty=b.y-d.y;
    float ix=-sg*ty, iy=sg*tx;
    y[p1]    = make_float2(acx+bdx, acy+bdy);
    y[p1+4]  = make_float2(sx+ix,  sy+iy);
    y[p1+8]  = make_float2(acx-bdx, acy-bdy);
    y[p1+12] = make_float2(sx-ix,  sy-iy);
  }
  #pragma unroll
  for (int i=0;i<16;i++) x[i]=y[i];
}

// x[m] *= exp(SGN*2*pi*i*j*m/den) via 2-level register table (no memory)
template<int SGN>
__device__ __forceinline__ void twiddle_apply(float2 x[16], int j, float invden){
  float th = (float)SGN * 6.28318530717958647f * (float)j * invden;
  float s, c; __sincosf(th, &s, &c);
  float2 w1 = make_float2(c, s);
  float2 w2 = cmul(w1,w1), w3 = cmul(w2,w1), w4 = cmul(w2,w2);
  float2 w8 = cmul(w4,w4), w12 = cmul(w8,w4);
  float2 wl[4] = {make_float2(1.f,0.f), w1, w2, w3};
  float2 wh[4] = {make_float2(1.f,0.f), w4, w8, w12};
  #pragma unroll
  for (int m=1;m<16;m++){
    float2 tw = cmul(wh[m>>2], wl[m&3]);
    x[m] = cmul(x[m], tw);
  }
}

// Stockham radix-16, 3 stages, in-place in lds (read/write phases barrier-separated).
// On entry x[m] = data[t + 256m]; on exit lds[swz(f)] holds ordered transform.
template<int SGN>
__device__ __forceinline__ void fft_stages(float2* lds, float2 x[16], int t){
  // stage 0: Ls=1 (j=0, no twiddle); dst = 16t + p
  dft16<SGN>(x);
  #pragma unroll
  for (int p=0;p<16;p++) lds[swz(t*16+p)] = x[p];
  __syncthreads();
  // stage 1: Ls=16
  #pragma unroll
  for (int m=0;m<16;m++) x[m] = lds[swz(t + 256*m)];
  __syncthreads();
  twiddle_apply<SGN>(x, t&15, 1.0f/256.0f);
  dft16<SGN>(x);
  {
    int base = (t>>4)*256 + (t&15);
    #pragma unroll
    for (int p=0;p<16;p++) lds[swz(base + 16*p)] = x[p];
  }
  __syncthreads();
  // stage 2: Ls=256
  #pragma unroll
  for (int m=0;m<16;m++) x[m] = lds[swz(t + 256*m)];
  __syncthreads();
  twiddle_apply<SGN>(x, t, 1.0f/4096.0f);
  dft16<SGN>(x);
  #pragma unroll
  for (int p=0;p<16;p++) lds[swz(t + 256*p)] = x[p];
  __syncthreads();
}

// forward: block = (bh, dgroup of 4). X = Q + iK, FFT, hermitian split,
// accumulate products in registers over 4 d; store partial to Spart[bh*16+g].
__global__ __launch_bounds__(256) void k_fft_fwd(const float* __restrict__ Qt, const float* __restrict__ Kt,
                                                 float* __restrict__ Spart){
  __shared__ float2 lds[4096];
  const int bh = blockIdx.x >> 4, g = blockIdx.x & 15;
  const int t = threadIdx.x;
  float2 pacc[16];
  #pragma unroll
  for (int i=0;i<16;i++) pacc[i]=make_float2(0.f,0.f);
  for (int dd=0; dd<4; ++dd){
    const size_t base = ((size_t)bh*DK + g*4 + dd)*LL;
    float2 x[16];
    #pragma unroll
    for (int m=0;m<16;m++){
      int n = t + 256*m;
      x[m] = make_float2(Qt[base+n], Kt[base+n]);
    }
    fft_stages<-1>(lds, x, t);
    #pragma unroll
    for (int i=0;i<16;i++){
      int f = t + 256*i;
      float2 A = lds[swz(f)];
      float2 Bv = lds[swz((LL-f)&(LL-1))];
      float qr = 0.5f*(A.x+Bv.x), qi = 0.5f*(A.y-Bv.y);
      float kr = 0.5f*(A.y+Bv.y), ki = -0.5f*(A.x-Bv.x);
      pacc[i].x += qr*kr + qi*ki;   // q * conj(k)
      pacc[i].y += qi*kr - qr*ki;
    }
    __syncthreads();
  }
  float2* Sp = (float2*)Spart + (size_t)blockIdx.x*LL;
  #pragma unroll
  for (int i=0;i<16;i++) Sp[t + 256*i] = pacc[i];
}

// inverse + top-8 + softmax: one block per (b,h); sums the 16 partials.
__global__ __launch_bounds__(256) void k_ifft_topk(const float* __restrict__ Spart,
                                                   float* __restrict__ w8, int* __restrict__ idx8){
  __shared__ float2 lds[4096];
  __shared__ float c[4096];
  __shared__ float rv[256];
  __shared__ int   ri[256];
  __shared__ float topv[8];
  __shared__ int   topi[8];
  const int bh = blockIdx.x, t = threadIdx.x;
  float2 x[16];
  #pragma unroll
  for (int m=0;m<16;m++){
    float2 acc = make_float2(0.f,0.f);
    int n = t + 256*m;
    for (int g2=0; g2<16; ++g2){
      float2 v = ((const float2*)Spart)[((size_t)bh*16+g2)*LL + n];
      acc.x += v.x; acc.y += v.y;
    }
    x[m] = acc;
  }
  fft_stages<1>(lds, x, t);
  const float scale = 1.0f/((float)LL * (float)DK);
  #pragma unroll
  for (int m=0;m<16;m++){ int f=t+256*m; c[f] = lds[swz(f)].x * scale; }
  __syncthreads();
  for (int kk=0; kk<8; kk++){
    float bv = -3.4e38f; int bi = 0;
    #pragma unroll
    for (int i=0;i<16;i++){
      int f = t + 256*i;
      float v = c[f];
      if (v > bv || (v == bv && f < bi)) { bv = v; bi = f; }
    }
    rv[t]=bv; ri[t]=bi;
    __syncthreads();
    for (int off=128; off>0; off>>=1){
      if (t < off){
        float ov = rv[t+off]; int oi = ri[t+off];
        if (ov > rv[t] || (ov == rv[t] && oi < ri[t])) { rv[t]=ov; ri[t]=oi; }
      }
      __syncthreads();
    }
    if (t==0){ topv[kk]=rv[0]; topi[kk]=ri[0]; c[ri[0]] = -3.0e38f; }
    __syncthreads();
  }
  if (t==0){
    float m = topv[0];
    float e[8], sum=0.f;
    for (int k=0;k<8;k++){ e[k]=__expf(topv[k]-m); sum+=e[k]; }
    for (int k=0;k<8;k++){ w8[bh*8+k]=e[k]/sum; idx8[bh*8+k]=topi[k]; }
  }
}

// ---------------- roll-gather ----------------
__global__ __launch_bounds__(256) void k_gather(const unsigned short* __restrict__ Vh,
                                                const float* __restrict__ w8, const int* __restrict__ idx8,
                                                unsigned short* __restrict__ Ob){
  const int blk = blockIdx.x;
  const int bh = blk >> 6;
  const int l0 = (blk & 63) * 64;
  const int b = bh >> 4, h = bh & 15;
  float w[8]; int ix[8];
  #pragma unroll
  for (int k=0;k<8;k++){ w[k]=w8[bh*8+k]; ix[k]=idx8[bh*8+k]; }
  const int tid = threadIdx.x;
  for (int it=0; it<16; ++it){
    int e = it*256 + tid;
    int lo = e >> 6, d = e & 63;
    int l = l0 + lo;
    float acc = 0.f;
    #pragma unroll
    for (int k=0;k<8;k++){
      int sl = (l + ix[k]) & (LL-1);
      acc += w[k] * bf2f(Vh[((size_t)bh*LL + sl)*DK + d]);
    }
    Ob[((size_t)(b*LL + l))*DM + h*DK + d] = f2bf(acc);
  }
}

// ---------------- launch ----------------
extern "C" void kernel_launch(void* const* d_in, const int* in_sizes, int n_in,
                              void* d_out, int out_size, void* d_ws, size_t ws_size,
                              hipStream_t stream) {
  const float* query = (const float*)d_in[0];
  const float* key   = (const float*)d_in[1];
  const float* value = (const float*)d_in[2];
  const float* Wq = (const float*)d_in[3];
  const float* bq = (const float*)d_in[4];
  const float* Wk = (const float*)d_in[5];
  const float* bk = (const float*)d_in[6];
  const float* Wv = (const float*)d_in[7];
  const float* bv = (const float*)d_in[8];
  const float* Wo = (const float*)d_in[9];
  const float* bo = (const float*)d_in[10];
  float* out = (float*)d_out;

  char* ws = (char*)d_ws;
  size_t off = 0;
  auto take = [&](size_t b)->char*{ char* p = ws + off; off += (b + 255) & ~(size_t)255; return p; };
  short* Xhi = (short*)take((size_t)MTOT*DM*2);        // 16MB (also reused as Ob)
  short* Xlo = (short*)take((size_t)MTOT*DM*2);        // 16MB (reused as Spart after last use)
  short* Wth = (short*)take((size_t)4*DM*DM*2);        // 8MB
  short* Wtl = (short*)take((size_t)2*DM*DM*2);        // 4MB
  float* Qt  = (float*)take((size_t)2*NH*DK*LL*4);     // 32MB [bh][d][l]
  float* Kt  = (float*)take((size_t)2*NH*DK*LL*4);     // 32MB
  unsigned short* Vh = (unsigned short*)take((size_t)2*NH*LL*DK*2); // 16MB [bh][l][d]
  float* w8  = (float*)take(32*8*4);
  int*  idx8 = (int*)take(32*8*4);
  float* Spart = (float*)Xlo;  // 32*16*4096*2*4 = 16MB, alias: Xlo dead after K-projection

  const int n4 = MTOT*DM/4;

  k_conv_wt<<<dim3(16,16,4),256,0,stream>>>(Wq,Wk,Wv,Wo,(unsigned short*)Wth,(unsigned short*)Wtl);

  k_conv_x_split<<<n4/256,256,0,stream>>>(query,(unsigned short*)Xhi,(unsigned short*)Xlo,n4);
  k_gemm_split<<<dim3(64,8),256,0,stream>>>(Xhi, Xlo, Wth, Wtl, bq, Qt);

  k_conv_x_split<<<n4/256,256,0,stream>>>(key,(unsigned short*)Xhi,(unsigned short*)Xlo,n4);
  k_gemm_split<<<dim3(64,8),256,0,stream>>>(Xhi, Xlo, Wth + (size_t)DM*DM, Wtl + (size_t)DM*DM, bk, Kt);

  k_conv_x<<<n4/256,256,0,stream>>>(value,(unsigned short*)Xhi,n4);
  k_gemm_plain<1><<<dim3(64,8),256,0,stream>>>(Xhi, Wth + (size_t)2*DM*DM, bv, nullptr, Vh);

  k_fft_fwd<<<512,256,0,stream>>>(Qt, Kt, Spart);
  k_ifft_topk<<<32,256,0,stream>>>(Spart, w8, idx8);
  k_gather<<<2048,256,0,stream>>>(Vh, w8, idx8, (unsigned short*)Xhi);

  k_gemm_plain<2><<<dim3(64,8),256,0,stream>>>(Xhi, Wth + (size_t)3*DM*DM, bo, out, nullptr);
}